// Round 1
// 248.460 us; speedup vs baseline: 1.1711x; 1.1711x over previous
//
#include <hip/hip_runtime.h>
#include <hip/hip_bf16.h>
#include <math.h>

#define HID 53

typedef __bf16 bf16x8 __attribute__((ext_vector_type(8)));
typedef float f32x4 __attribute__((ext_vector_type(4)));

__device__ __forceinline__ unsigned f2u(float f) { return __builtin_bit_cast(unsigned, f); }
__device__ __forceinline__ float u2f(unsigned u) { return __builtin_bit_cast(float, u); }
__device__ __forceinline__ bf16x8 ld8(const ushort* p) {
    return __builtin_bit_cast(bf16x8, *(const uint4*)p);
}
__device__ __forceinline__ unsigned rnb(float f) {
    unsigned u = f2u(f);
    return (u + 0x7FFFu + ((u >> 16) & 1u)) >> 16;
}
__device__ __forceinline__ void split3rn(float f, unsigned& h, unsigned& m, unsigned& l) {
    h = rnb(f);
    float r1 = f - u2f(h << 16);
    m = rnb(r1);
    float r2 = r1 - u2f(m << 16);
    l = rnb(r2);
}

// hw bf16 round-to-nearest-even cast; bit-identical to rnb() but ~2-3 VALU
// ops instead of ~6 (v_cvt_pk_bf16_f32 pairs under the compiler).
__device__ __forceinline__ ushort f2bf(float f) {
    return __builtin_bit_cast(ushort, (__bf16)f);
}
__device__ __forceinline__ float bfbits2f(ushort h) { return u2f((unsigned)h << 16); }
__device__ __forceinline__ void split3c(float f, ushort& h, ushort& m, ushort& l) {
    h = f2bf(f);
    float r1 = f - bfbits2f(h);
    m = f2bf(r1);
    float r2 = r1 - bfbits2f(m);
    l = f2bf(r2);
}

// ---------------- K1: per-(b,c) spatial mean * gap_scaler ----------------
__global__ __launch_bounds__(256) void mean_kernel(
    const float* __restrict__ x, const float* __restrict__ gap,
    float* __restrict__ gmu)
{
    const int bc = blockIdx.x;
    const float* p = x + (size_t)bc * 4096;
    float s = 0.f;
    for (int i = threadIdx.x * 4; i < 4096; i += 256 * 4) {
        float4 v = *(const float4*)(p + i);
        s += v.x + v.y + v.z + v.w;
    }
    s += __shfl_xor(s, 1);
    s += __shfl_xor(s, 2);
    s += __shfl_xor(s, 4);
    s += __shfl_xor(s, 8);
    s += __shfl_xor(s, 16);
    s += __shfl_xor(s, 32);
    __shared__ float ls[4];
    if ((threadIdx.x & 63) == 0) ls[threadIdx.x >> 6] = s;
    __syncthreads();
    if (threadIdx.x == 0) {
        float t = ls[0] + ls[1] + ls[2] + ls[3];
        gmu[bc] = gap[bc & 255] * (t * (1.f / 4096.f));
    }
}

// ---------------- K2a: xq via 6-term split-bf16 MFMA -----------------------
// Same GEMM shape/structure as gemm_val_kernel, but with a third split
// plane (lo) and six MFMA terms per k-tile: hh + hm + mh + mm + hl + lh.
// Missing product mass (ml+lm+ll) ~ 3*2^-27 relative — below fp32 product
// rounding (2^-24). hh accumulates in its own accumulator (accM: 256 fp32
// roundings at full magnitude, same noise profile as the round-1 fp32 fmaf
// chain); the five small terms (<=2^-9 relative) accumulate in accS and are
// added once at the end. Keeps the sim/argmax path in the fp32 error class
// while moving 8.6 GFLOP from the 157 TF vector pipe to the matrix pipe.
__global__ __launch_bounds__(256, 2) void gemm_xq6_kernel(
    const float* __restrict__ X, const float* __restrict__ gmu,
    const float* __restrict__ W,
    const float* __restrict__ bias_g,
    float* __restrict__ dst)
{
    __shared__ __align__(16) ushort Ahi[128 * 40];
    __shared__ __align__(16) ushort Amd[128 * 40];
    __shared__ __align__(16) ushort Alo[128 * 40];
    __shared__ __align__(16) ushort Bhi[128 * 40];
    __shared__ __align__(16) ushort Bmd[128 * 40];
    __shared__ __align__(16) ushort Blo[128 * 40];

    const int tid  = threadIdx.x;
    const int Nblk = blockIdx.x, Mblk = blockIdx.y, b = blockIdx.z;
    const int lane = tid & 63, wav = tid >> 6;
    const int wm = wav >> 1, wn = wav & 1;
    const int lr = lane & 15, q = lane >> 4;

    f32x4 accM[4][4], accS[4][4];
#pragma unroll
    for (int i = 0; i < 4; ++i)
#pragma unroll
        for (int j = 0; j < 4; ++j) {
            accM[i][j] = (f32x4){0.f, 0.f, 0.f, 0.f};
            accS[i][j] = (f32x4){0.f, 0.f, 0.f, 0.f};
        }

    const bool isB = (tid < 128);
    float4 regs[8];
    float gval0 = 0.f, gval1 = 0.f;
    const float* srcB = X;
    const float* wrow = W;
    int kp = 0, q8 = 0, arow = 0;
    if (isB) {
        kp = tid >> 3; q8 = tid & 7;
        srcB = X + ((size_t)b << 20) + (size_t)(2 * kp) * 4096 + Nblk * 128 + q8 * 4;
    } else {
        arow = tid - 128;
        int o = Mblk * 128 + arow;
        wrow = W + (size_t)o * 256;
    }

    auto LOADR = [&](int ks) {
        const int k0 = ks * 32;
        if (isB) {
            const float* p = srcB + (size_t)k0 * 4096;
#pragma unroll
            for (int i = 0; i < 4; ++i) {
                regs[i]     = *(const float4*)(p + i * 32);
                regs[i + 4] = *(const float4*)(p + 4096 + i * 32);
            }
            gval0 = gmu[b * 256 + k0 + 2 * kp];
            gval1 = gmu[b * 256 + k0 + 2 * kp + 1];
        } else {
            const float* p = wrow + k0;
#pragma unroll
            for (int i = 0; i < 8; ++i) regs[i] = *(const float4*)(p + i * 4);
        }
    };

    auto WRITE = [&]() {
        if (isB) {
#pragma unroll
            for (int i = 0; i < 4; ++i) {
                float4 r0 = regs[i], r1 = regs[i + 4];
                r0.x += gval0; r0.y += gval0; r0.z += gval0; r0.w += gval0;
                r1.x += gval1; r1.y += gval1; r1.z += gval1; r1.w += gval1;
                const float* p0 = &r0.x;
                const float* p1 = &r1.x;
#pragma unroll
                for (int e = 0; e < 4; ++e) {
                    ushort h0, m0, l0, h1, m1, l1;
                    split3c(p0[e], h0, m0, l0);
                    split3c(p1[e], h1, m1, l1);
                    int n = q8 * 4 + i * 32 + e;
                    ((unsigned*)Bhi)[n * 20 + kp] = (unsigned)h0 | ((unsigned)h1 << 16);
                    ((unsigned*)Bmd)[n * 20 + kp] = (unsigned)m0 | ((unsigned)m1 << 16);
                    ((unsigned*)Blo)[n * 20 + kp] = (unsigned)l0 | ((unsigned)l1 << 16);
                }
            }
        } else {
#pragma unroll
            for (int i = 0; i < 8; ++i) {
                float4 r = regs[i];
                ushort h0, m0, l0, h1, m1, l1, h2, m2, l2, h3, m3, l3;
                split3c(r.x, h0, m0, l0);
                split3c(r.y, h1, m1, l1);
                split3c(r.z, h2, m2, l2);
                split3c(r.w, h3, m3, l3);
                uint2 h = {(unsigned)h0 | ((unsigned)h1 << 16),
                           (unsigned)h2 | ((unsigned)h3 << 16)};
                uint2 m = {(unsigned)m0 | ((unsigned)m1 << 16),
                           (unsigned)m2 | ((unsigned)m3 << 16)};
                uint2 l = {(unsigned)l0 | ((unsigned)l1 << 16),
                           (unsigned)l2 | ((unsigned)l3 << 16)};
                *(uint2*)&Ahi[arow * 40 + i * 4] = h;
                *(uint2*)&Amd[arow * 40 + i * 4] = m;
                *(uint2*)&Alo[arow * 40 + i * 4] = l;
            }
        }
    };

    LOADR(0);
    for (int ks = 0; ks < 8; ++ks) {
        WRITE();
        __syncthreads();
        if (ks < 7) LOADR(ks + 1);

        // pass 1: terms using ah/ad (hh into accM; hm,mh,mm,hl into accS)
        bf16x8 ah[4], ad[4];
#pragma unroll
        for (int mt = 0; mt < 4; ++mt) {
            int row = wm * 64 + mt * 16 + lr;
            ah[mt] = ld8(&Ahi[row * 40 + q * 8]);
            ad[mt] = ld8(&Amd[row * 40 + q * 8]);
        }
#pragma unroll
        for (int nt = 0; nt < 4; ++nt) {
            int row = wn * 64 + nt * 16 + lr;
            bf16x8 bh = ld8(&Bhi[row * 40 + q * 8]);
            bf16x8 bd = ld8(&Bmd[row * 40 + q * 8]);
            bf16x8 bl = ld8(&Blo[row * 40 + q * 8]);
#pragma unroll
            for (int mt = 0; mt < 4; ++mt) {
                accS[mt][nt] = __builtin_amdgcn_mfma_f32_16x16x32_bf16(ah[mt], bd, accS[mt][nt], 0, 0, 0);
                accS[mt][nt] = __builtin_amdgcn_mfma_f32_16x16x32_bf16(ad[mt], bh, accS[mt][nt], 0, 0, 0);
                accS[mt][nt] = __builtin_amdgcn_mfma_f32_16x16x32_bf16(ad[mt], bd, accS[mt][nt], 0, 0, 0);
                accS[mt][nt] = __builtin_amdgcn_mfma_f32_16x16x32_bf16(ah[mt], bl, accS[mt][nt], 0, 0, 0);
                accM[mt][nt] = __builtin_amdgcn_mfma_f32_16x16x32_bf16(ah[mt], bh, accM[mt][nt], 0, 0, 0);
            }
        }
        // pass 2: lh terms (al loaded after ad dies — keeps peak VGPR down)
        bf16x8 al[4];
#pragma unroll
        for (int mt = 0; mt < 4; ++mt) {
            int row = wm * 64 + mt * 16 + lr;
            al[mt] = ld8(&Alo[row * 40 + q * 8]);
        }
#pragma unroll
        for (int nt = 0; nt < 4; ++nt) {
            int row = wn * 64 + nt * 16 + lr;
            bf16x8 bh2 = ld8(&Bhi[row * 40 + q * 8]);
#pragma unroll
            for (int mt = 0; mt < 4; ++mt)
                accS[mt][nt] = __builtin_amdgcn_mfma_f32_16x16x32_bf16(al[mt], bh2, accS[mt][nt], 0, 0, 0);
        }
        __syncthreads();
    }

    const size_t bbase = (size_t)b << 20;
    const int tb = Nblk * 128 + wn * 64 + lr;
    int offN[4];
#pragma unroll
    for (int nt = 0; nt < 4; ++nt) {
        int t = tb + nt * 16;
        offN[nt] = ((t >> 11) & 1) * 65536 + ((t >> 5) & 1) * 32768
                 + ((t >> 6) & 31) * 32 + (t & 31);
    }
#pragma unroll
    for (int mt = 0; mt < 4; ++mt) {
#pragma unroll
        for (int r = 0; r < 4; ++r) {
            int oc = Mblk * 128 + wm * 64 + mt * 16 + q * 4 + r;
            float bias = bias_g[oc];
            size_t offM = (size_t)(oc >> 5) * 131072 + (size_t)(oc & 31) * 1024;
#pragma unroll
            for (int nt = 0; nt < 4; ++nt)
                dst[bbase + offM + offN[nt]] = accM[mt][nt][r] + accS[mt][nt][r] + bias;
        }
    }
}

// ---------------- K2b: split-bf16 MFMA GEMM (value path) -------------------
__global__ __launch_bounds__(256, 2) void gemm_val_kernel(
    const float* __restrict__ X, const float* __restrict__ gmu,
    const float* __restrict__ W,
    const float* __restrict__ bias_g,
    float* __restrict__ dst)
{
    __shared__ __align__(16) ushort Ahi[128 * 40];
    __shared__ __align__(16) ushort Amd[128 * 40];
    __shared__ __align__(16) ushort Bhi[128 * 40];
    __shared__ __align__(16) ushort Bmd[128 * 40];

    const int tid  = threadIdx.x;
    const int Nblk = blockIdx.x, Mblk = blockIdx.y, b = blockIdx.z;
    const int lane = tid & 63, wav = tid >> 6;
    const int wm = wav >> 1, wn = wav & 1;
    const int lr = lane & 15, q = lane >> 4;

    f32x4 acc[4][4];
#pragma unroll
    for (int i = 0; i < 4; ++i)
#pragma unroll
        for (int j = 0; j < 4; ++j) acc[i][j] = (f32x4){0.f, 0.f, 0.f, 0.f};

    const bool isB = (tid < 128);
    float4 regs[8];
    float gval0 = 0.f, gval1 = 0.f;
    const float* srcB = X;
    const float* wrow = W;
    int kp = 0, q8 = 0, arow = 0;
    if (isB) {
        kp = tid >> 3; q8 = tid & 7;
        srcB = X + ((size_t)b << 20) + (size_t)(2 * kp) * 4096 + Nblk * 128 + q8 * 4;
    } else {
        arow = tid - 128;
        int o = Mblk * 128 + arow;
        wrow = W + (size_t)o * 256;
    }

    auto LOADR = [&](int ks) {
        const int k0 = ks * 32;
        if (isB) {
            const float* p = srcB + (size_t)k0 * 4096;
#pragma unroll
            for (int i = 0; i < 4; ++i) {
                regs[i]     = *(const float4*)(p + i * 32);
                regs[i + 4] = *(const float4*)(p + 4096 + i * 32);
            }
            gval0 = gmu[b * 256 + k0 + 2 * kp];
            gval1 = gmu[b * 256 + k0 + 2 * kp + 1];
        } else {
            const float* p = wrow + k0;
#pragma unroll
            for (int i = 0; i < 8; ++i) regs[i] = *(const float4*)(p + i * 4);
        }
    };

    auto WRITE = [&]() {
        if (isB) {
#pragma unroll
            for (int i = 0; i < 4; ++i) {
                float4 r0 = regs[i], r1 = regs[i + 4];
                r0.x += gval0; r0.y += gval0; r0.z += gval0; r0.w += gval0;
                r1.x += gval1; r1.y += gval1; r1.z += gval1; r1.w += gval1;
                const float* p0 = &r0.x;
                const float* p1 = &r1.x;
#pragma unroll
                for (int e = 0; e < 4; ++e) {
                    unsigned h0, m0, l0, h1, m1, l1;
                    split3rn(p0[e], h0, m0, l0);
                    split3rn(p1[e], h1, m1, l1);
                    int n = q8 * 4 + i * 32 + e;
                    ((unsigned*)Bhi)[n * 20 + kp] = h0 | (h1 << 16);
                    ((unsigned*)Bmd)[n * 20 + kp] = m0 | (m1 << 16);
                }
            }
        } else {
#pragma unroll
            for (int i = 0; i < 8; ++i) {
                float4 r = regs[i];
                unsigned h0, m0, l0, h1, m1, l1, h2, m2, l2, h3, m3, l3;
                split3rn(r.x, h0, m0, l0);
                split3rn(r.y, h1, m1, l1);
                split3rn(r.z, h2, m2, l2);
                split3rn(r.w, h3, m3, l3);
                uint2 h = {h0 | (h1 << 16), h2 | (h3 << 16)};
                uint2 m = {m0 | (m1 << 16), m2 | (m3 << 16)};
                *(uint2*)&Ahi[arow * 40 + i * 4] = h;
                *(uint2*)&Amd[arow * 40 + i * 4] = m;
            }
        }
    };

    LOADR(0);
    for (int ks = 0; ks < 8; ++ks) {
        WRITE();
        __syncthreads();
        if (ks < 7) LOADR(ks + 1);
        bf16x8 ah[4], ad[4];
#pragma unroll
        for (int mt = 0; mt < 4; ++mt) {
            int row = wm * 64 + mt * 16 + lr;
            ah[mt] = ld8(&Ahi[row * 40 + q * 8]);
            ad[mt] = ld8(&Amd[row * 40 + q * 8]);
        }
#pragma unroll
        for (int nt = 0; nt < 4; ++nt) {
            int row = wn * 64 + nt * 16 + lr;
            bf16x8 bh = ld8(&Bhi[row * 40 + q * 8]);
            bf16x8 bd = ld8(&Bmd[row * 40 + q * 8]);
#pragma unroll
            for (int mt = 0; mt < 4; ++mt) {
                acc[mt][nt] = __builtin_amdgcn_mfma_f32_16x16x32_bf16(ah[mt], bd, acc[mt][nt], 0, 0, 0);
                acc[mt][nt] = __builtin_amdgcn_mfma_f32_16x16x32_bf16(ad[mt], bh, acc[mt][nt], 0, 0, 0);
                acc[mt][nt] = __builtin_amdgcn_mfma_f32_16x16x32_bf16(ah[mt], bh, acc[mt][nt], 0, 0, 0);
            }
        }
        __syncthreads();
    }

    const size_t bbase = (size_t)b << 20;
    const int tb = Nblk * 128 + wn * 64 + lr;
    int offN[4];
#pragma unroll
    for (int nt = 0; nt < 4; ++nt) {
        int t = tb + nt * 16;
        offN[nt] = ((t >> 11) & 1) * 65536 + ((t >> 5) & 1) * 32768
                 + ((t >> 6) & 31) * 32 + (t & 31);
    }
#pragma unroll
    for (int mt = 0; mt < 4; ++mt) {
#pragma unroll
        for (int r = 0; r < 4; ++r) {
            int oc = Mblk * 128 + wm * 64 + mt * 16 + q * 4 + r;
            float bias = bias_g[oc];
            size_t offM = (size_t)(oc >> 5) * 131072 + (size_t)(oc & 31) * 1024;
#pragma unroll
            for (int nt = 0; nt < 4; ++nt)
                dst[bbase + offM + offN[nt]] = acc[mt][nt][r] + bias;
        }
    }
}

// ---------------- K3a: centers (pool + MLP + maxpool), deterministic -------
__global__ __launch_bounds__(256) void centers_kernel(
    const float* __restrict__ xqb, const float* __restrict__ valb,
    const float* __restrict__ w1g, const float* __restrict__ b1g,
    const float* __restrict__ w2g, const float* __restrict__ b2g,
    float* __restrict__ cenbuf)
{
    const int bp = blockIdx.x;
    const float* src = (blockIdx.y ? valb : xqb) + (size_t)bp * 32768;
    const int t = threadIdx.x;

    __shared__ float pz[2048];
    __shared__ float ybuf[64 * HID];
    __shared__ float w1s[HID * 32 + HID];
    __shared__ float w2s[32 * HID + 32];
    __shared__ float avg2[128];

    for (int i = t; i < HID * 32; i += 256) w1s[i] = w1g[i];
    if (t < HID) w1s[HID * 32 + t] = b1g[t];
    for (int i = t; i < 32 * HID; i += 256) w2s[i] = w2g[i];
    if (t < 32) w2s[32 * HID + t] = b2g[t];

    {
        int c = t >> 3, gw = t & 7;
        const float* p = src + c * 1024 + gw * 128;
        float cell[8];
#pragma unroll
        for (int i = 0; i < 4; ++i) {
#pragma unroll
            for (int gh = 0; gh < 8; ++gh) {
                float4 v = *(const float4*)(p + i * 32 + gh * 4);
                float r = (v.x + v.y) + (v.z + v.w);
                cell[gh] = (i == 0) ? r : cell[gh] + r;
            }
        }
#pragma unroll
        for (int gh = 0; gh < 8; ++gh)
            pz[c * 64 + gw * 8 + gh] = cell[gh] * 0.0625f;
    }
    __syncthreads();

    if (t < 128) {
        int qq = t >> 5, c = t & 31, qw = qq >> 1, qh = qq & 1;
        float s = 0.f;
        for (int a = 0; a < 4; ++a)
            for (int e = 0; e < 4; ++e)
                s += pz[c * 64 + (qw * 4 + a) * 8 + (qh * 4 + e)];
        avg2[t] = s * 0.0625f;
    }
    for (int tt = t; tt < 64 * HID; tt += 256) {
        int g = tt / HID, h = tt - g * HID;
        float a = w1s[HID * 32 + h];
        for (int c = 0; c < 32; ++c) a += pz[c * 64 + g] * w1s[h * 32 + c];
        ybuf[g * HID + h] = 0.5f * a * (1.f + erff(a * 0.70710678118654752f));
    }
    __syncthreads();

    for (int tt = t; tt < 2048; tt += 256) {
        int g = tt >> 5, c = tt & 31;
        float a = w2s[32 * HID + c];
        for (int h = 0; h < HID; ++h) a += ybuf[g * HID + h] * w2s[c * HID + h];
        pz[g * 32 + c] = a;
    }
    __syncthreads();

    if (t < 128) {
        int qq = t >> 5, c = t & 31, qw = qq >> 1, qh = qq & 1;
        float m = -1e30f;
        for (int a = 0; a < 4; ++a)
            for (int e = 0; e < 4; ++e)
                m = fmaxf(m, pz[((qw * 4 + a) * 8 + qh * 4 + e) * 32 + c]);
        cenbuf[blockIdx.y * 65536 + bp * 128 + t] = avg2[t] + m;
    }
}

// ---------------- K3b: assign + combine (no dispatch write) ----------------
__global__ __launch_bounds__(1024) void assign_kernel(
    const float* __restrict__ xqb, const float* __restrict__ valb,
    const float* __restrict__ cenbuf,
    const float* __restrict__ alphap, const float* __restrict__ betap,
    float* __restrict__ wbpk, float* __restrict__ outcg)
{
    const int bp = blockIdx.x;
    const int n  = threadIdx.x;
    const int lane = n & 63;

    __shared__ float cen0s[128], cen1s[128];
    __shared__ float wbuf[1024];
    __shared__ int   bbuf[1024];
    __shared__ float csum[32][4];
    __shared__ float ccnt[4];

    if (n < 128) cen0s[n] = cenbuf[bp * 128 + n];
    else if (n < 256) cen1s[n - 128] = cenbuf[65536 + bp * 128 + (n - 128)];
    if (n < 4) ccnt[n] = 0.f;
    __syncthreads();

    float rn[4];
#pragma unroll
    for (int m = 0; m < 4; ++m) {
        float ssn = 0.f;
        for (int c = 0; c < 32; ++c) { float tt = cen0s[m * 32 + c]; ssn += tt * tt; }
        rn[m] = 1.f / fmaxf(sqrtf(ssn), 1e-12f);
    }

    const float* px = xqb + (size_t)bp * 32768 + n;
    float ss = 0.f, d0 = 0.f, d1 = 0.f, d2 = 0.f, d3 = 0.f;
#pragma unroll
    for (int c = 0; c < 32; ++c) {
        float v = px[(size_t)c << 10];
        ss += v * v;
        d0 += cen0s[0 * 32 + c] * v;
        d1 += cen0s[1 * 32 + c] * v;
        d2 += cen0s[2 * 32 + c] * v;
        d3 += cen0s[3 * 32 + c] * v;
    }
    const float rx = 1.f / fmaxf(sqrtf(ss), 1e-12f);
    const float alpha = alphap[0], beta = betap[0];
    float dm[4] = {d0, d1, d2, d3};
    float best = -1.f;
    int bidx = 0;
#pragma unroll
    for (int m = 0; m < 4; ++m) {
        float t = beta + alpha * (dm[m] * rn[m] * rx);
        float s = 1.f / (1.f + expf(-t));
        if (m == 0 || s > best) { best = s; bidx = m; }
    }
    wbuf[n] = best;
    bbuf[n] = bidx;
    wbpk[(size_t)bp * 1024 + n] = u2f((f2u(best) & ~3u) | (unsigned)bidx);

#pragma unroll
    for (int m = 0; m < 4; ++m) {
        unsigned long long bl = __ballot(bidx == m);
        if (lane == 0) atomicAdd(&ccnt[m], (float)__popcll(bl));
    }
    __syncthreads();

    {
        const int c = n >> 5, l = n & 31;
        const float* pv = valb + (size_t)bp * 32768 + c * 1024 + l;
        float a0 = 0.f, a1 = 0.f, a2 = 0.f, a3 = 0.f;
#pragma unroll
        for (int i = 0; i < 32; ++i) {
            float v = pv[i * 32];
            int t = i * 32 + l;
            float p = wbuf[t] * v;
            int m = bbuf[t];
            a0 += (m == 0) ? p : 0.f;
            a1 += (m == 1) ? p : 0.f;
            a2 += (m == 2) ? p : 0.f;
            a3 += (m == 3) ? p : 0.f;
        }
#pragma unroll
        for (int off = 1; off < 32; off <<= 1) {
            a0 += __shfl_xor(a0, off);
            a1 += __shfl_xor(a1, off);
            a2 += __shfl_xor(a2, off);
            a3 += __shfl_xor(a3, off);
        }
        if (l == 0) {
            csum[c][0] = a0; csum[c][1] = a1; csum[c][2] = a2; csum[c][3] = a3;
        }
    }
    __syncthreads();
    if (n < 128)
        outcg[(size_t)bp * 128 + n] =
            (csum[n & 31][n >> 5] + cen1s[n]) / (ccnt[n >> 5] + 1.f);
}

// ---------------- K4a: P[bp][m][o] = sum_c w2[o, head*32+c] * outc[m][c] ---
__global__ __launch_bounds__(256) void pmat_kernel(
    const float* __restrict__ outcg, const float* __restrict__ w2,
    float* __restrict__ P)
{
    const int bp = blockIdx.x;
    const int o  = threadIdx.x;
    __shared__ float oc[128];
    if (o < 128) oc[o] = outcg[(size_t)bp * 128 + o];
    __syncthreads();
    const int head = (bp >> 2) & 7;
    const float* wrow = w2 + (size_t)o * 256 + head * 32;
    float a0 = 0.f, a1 = 0.f, a2 = 0.f, a3 = 0.f;
#pragma unroll
    for (int c = 0; c < 32; ++c) {
        float wv = wrow[c];
        a0 = fmaf(wv, oc[c], a0);
        a1 = fmaf(wv, oc[32 + c], a1);
        a2 = fmaf(wv, oc[64 + c], a2);
        a3 = fmaf(wv, oc[96 + c], a3);
    }
    float* pb = P + (size_t)bp * 1024;
    pb[0 * 256 + o] = a0;
    pb[1 * 256 + o] = a1;
    pb[2 * 256 + o] = a2;
    pb[3 * 256 + o] = a3;
}

// ---------------- K4b: fused dispatch + fc2 --------------------------------
__global__ __launch_bounds__(1024) void fc2_dispatch_kernel(
    const float* __restrict__ P, const float* __restrict__ wbpk,
    const float* __restrict__ b2, float* __restrict__ out)
{
    const int ogrp = blockIdx.x, quad = blockIdx.y, b = blockIdx.z;
    const int n = threadIdx.x;
    const int wl = n >> 5, hl = n & 31;

    __shared__ float Pl[8][4][68];
    __shared__ float b2s[64];

    for (int i = n; i < 2048; i += 1024) {
        int h = i >> 8, rm = i & 255;
        int m = rm >> 6, j = rm & 63;
        int bp = b * 32 + h * 4 + quad;
        Pl[h][m][j] = P[(size_t)bp * 1024 + m * 256 + ogrp * 64 + j];
    }
    if (n < 64) b2s[n] = b2[ogrp * 64 + n];
    __syncthreads();

    float bst[8];
    int   mm[8];
#pragma unroll
    for (int h = 0; h < 8; ++h) {
        int bp = b * 32 + h * 4 + quad;
        unsigned u = f2u(wbpk[(size_t)bp * 1024 + n]);
        mm[h]  = (int)(u & 3u);
        bst[h] = u2f(u & ~3u);
    }

    const int fi = quad >> 1, fj = quad & 1;
    float* obp = out + (size_t)b * 1048576 + (size_t)ogrp * 64 * 4096
               + (size_t)(fi * 32 + wl) * 64 + (fj * 32 + hl);
#pragma unroll 4
    for (int j = 0; j < 64; ++j) {
        float s = b2s[j];
#pragma unroll
        for (int h = 0; h < 8; ++h)
            s = fmaf(bst[h], Pl[h][mm[h]][j], s);
        obp[(size_t)j * 4096] = s;
    }
}

// ---------------- launch ----------------
extern "C" void kernel_launch(void* const* d_in, const int* in_sizes, int n_in,
                              void* d_out, int out_size, void* d_ws, size_t ws_size,
                              hipStream_t stream) {
    const float* x     = (const float*)d_in[0];
    const float* gap   = (const float*)d_in[1];
    const float* wq    = (const float*)d_in[2];
    const float* bq    = (const float*)d_in[3];
    const float* wv    = (const float*)d_in[4];
    const float* bv    = (const float*)d_in[5];
    const float* w2    = (const float*)d_in[6];
    const float* b2    = (const float*)d_in[7];
    const float* alpha = (const float*)d_in[8];
    const float* beta  = (const float*)d_in[9];
    const float* ow1   = (const float*)d_in[10];
    const float* ob1   = (const float*)d_in[11];
    const float* ow2   = (const float*)d_in[12];
    const float* ob2   = (const float*)d_in[13];

    float* out  = (float*)d_out;
    float* gmu  = (float*)d_ws;                   // 4096
    float* valb = gmu + 4096;                     // 16.7M
    float* cenb = valb + (size_t)16777216;        // 131072
    float* wbpk = cenb + 131072;                  // 524288
    float* outc = wbpk + 524288;                  // 65536
    float* pmat = outc + 65536;                   // 524288
    float* xqb  = out;                            // d_out reused as xq scratch

    mean_kernel<<<4096, 256, 0, stream>>>(x, gap, gmu);
    gemm_xq6_kernel<<<dim3(32, 2, 16), 256, 0, stream>>>(x, gmu, wq, bq, xqb);
    gemm_val_kernel<<<dim3(32, 2, 16), 256, 0, stream>>>(x, gmu, wv, bv, valb);
    centers_kernel<<<dim3(512, 2), 256, 0, stream>>>(
        xqb, valb, ow1, ob1, ow2, ob2, cenb);
    assign_kernel<<<512, 1024, 0, stream>>>(
        xqb, valb, cenb, alpha, beta, wbpk, outc);
    pmat_kernel<<<512, 256, 0, stream>>>(outc, w2, pmat);
    fc2_dispatch_kernel<<<dim3(4, 4, 16), 1024, 0, stream>>>(
        pmat, wbpk, b2, out);
}

// Round 2
// 226.917 us; speedup vs baseline: 1.2823x; 1.0949x over previous
//
#include <hip/hip_runtime.h>
#include <hip/hip_bf16.h>
#include <math.h>

#define HID 53

typedef __bf16 bf16x8 __attribute__((ext_vector_type(8)));
typedef float f32x4 __attribute__((ext_vector_type(4)));

__device__ __forceinline__ unsigned f2u(float f) { return __builtin_bit_cast(unsigned, f); }
__device__ __forceinline__ float u2f(unsigned u) { return __builtin_bit_cast(float, u); }
__device__ __forceinline__ bf16x8 ld8(const ushort* p) {
    return __builtin_bit_cast(bf16x8, *(const uint4*)p);
}
__device__ __forceinline__ unsigned rnb(float f) {
    unsigned u = f2u(f);
    return (u + 0x7FFFu + ((u >> 16) & 1u)) >> 16;
}
__device__ __forceinline__ void split3rn(float f, unsigned& h, unsigned& m, unsigned& l) {
    h = rnb(f);
    float r1 = f - u2f(h << 16);
    m = rnb(r1);
    float r2 = r1 - u2f(m << 16);
    l = rnb(r2);
}

// hw bf16 round-to-nearest-even cast; bit-identical to rnb() but fewer VALU ops.
__device__ __forceinline__ ushort f2bf(float f) {
    return __builtin_bit_cast(ushort, (__bf16)f);
}
__device__ __forceinline__ float bfbits2f(ushort h) { return u2f((unsigned)h << 16); }
__device__ __forceinline__ void split3c(float f, ushort& h, ushort& m, ushort& l) {
    h = f2bf(f);
    float r1 = f - bfbits2f(h);
    m = f2bf(r1);
    float r2 = r1 - bfbits2f(m);
    l = f2bf(r2);
}

// ---------------- K1: per-(b,c) spatial mean * gap_scaler ----------------
__global__ __launch_bounds__(256) void mean_kernel(
    const float* __restrict__ x, const float* __restrict__ gap,
    float* __restrict__ gmu)
{
    const int bc = blockIdx.x;
    const float* p = x + (size_t)bc * 4096;
    float s = 0.f;
    for (int i = threadIdx.x * 4; i < 4096; i += 256 * 4) {
        float4 v = *(const float4*)(p + i);
        s += v.x + v.y + v.z + v.w;
    }
    s += __shfl_xor(s, 1);
    s += __shfl_xor(s, 2);
    s += __shfl_xor(s, 4);
    s += __shfl_xor(s, 8);
    s += __shfl_xor(s, 16);
    s += __shfl_xor(s, 32);
    __shared__ float ls[4];
    if ((threadIdx.x & 63) == 0) ls[threadIdx.x >> 6] = s;
    __syncthreads();
    if (threadIdx.x == 0) {
        float t = ls[0] + ls[1] + ls[2] + ls[3];
        gmu[bc] = gap[bc & 255] * (t * (1.f / 4096.f));
    }
}

// ---------------- K2a: xq via 6-term split-bf16 MFMA -----------------------
__global__ __launch_bounds__(256, 2) void gemm_xq6_kernel(
    const float* __restrict__ X, const float* __restrict__ gmu,
    const float* __restrict__ W,
    const float* __restrict__ bias_g,
    float* __restrict__ dst)
{
    __shared__ __align__(16) ushort Ahi[128 * 40];
    __shared__ __align__(16) ushort Amd[128 * 40];
    __shared__ __align__(16) ushort Alo[128 * 40];
    __shared__ __align__(16) ushort Bhi[128 * 40];
    __shared__ __align__(16) ushort Bmd[128 * 40];
    __shared__ __align__(16) ushort Blo[128 * 40];

    const int tid  = threadIdx.x;
    const int Nblk = blockIdx.x, Mblk = blockIdx.y, b = blockIdx.z;
    const int lane = tid & 63, wav = tid >> 6;
    const int wm = wav >> 1, wn = wav & 1;
    const int lr = lane & 15, q = lane >> 4;

    f32x4 accM[4][4], accS[4][4];
#pragma unroll
    for (int i = 0; i < 4; ++i)
#pragma unroll
        for (int j = 0; j < 4; ++j) {
            accM[i][j] = (f32x4){0.f, 0.f, 0.f, 0.f};
            accS[i][j] = (f32x4){0.f, 0.f, 0.f, 0.f};
        }

    const bool isB = (tid < 128);
    float4 regs[8];
    float gval0 = 0.f, gval1 = 0.f;
    const float* srcB = X;
    const float* wrow = W;
    int kp = 0, q8 = 0, arow = 0;
    if (isB) {
        kp = tid >> 3; q8 = tid & 7;
        srcB = X + ((size_t)b << 20) + (size_t)(2 * kp) * 4096 + Nblk * 128 + q8 * 4;
    } else {
        arow = tid - 128;
        int o = Mblk * 128 + arow;
        wrow = W + (size_t)o * 256;
    }

    auto LOADR = [&](int ks) {
        const int k0 = ks * 32;
        if (isB) {
            const float* p = srcB + (size_t)k0 * 4096;
#pragma unroll
            for (int i = 0; i < 4; ++i) {
                regs[i]     = *(const float4*)(p + i * 32);
                regs[i + 4] = *(const float4*)(p + 4096 + i * 32);
            }
            gval0 = gmu[b * 256 + k0 + 2 * kp];
            gval1 = gmu[b * 256 + k0 + 2 * kp + 1];
        } else {
            const float* p = wrow + k0;
#pragma unroll
            for (int i = 0; i < 8; ++i) regs[i] = *(const float4*)(p + i * 4);
        }
    };

    auto WRITE = [&]() {
        if (isB) {
#pragma unroll
            for (int i = 0; i < 4; ++i) {
                float4 r0 = regs[i], r1 = regs[i + 4];
                r0.x += gval0; r0.y += gval0; r0.z += gval0; r0.w += gval0;
                r1.x += gval1; r1.y += gval1; r1.z += gval1; r1.w += gval1;
                const float* p0 = &r0.x;
                const float* p1 = &r1.x;
#pragma unroll
                for (int e = 0; e < 4; ++e) {
                    ushort h0, m0, l0, h1, m1, l1;
                    split3c(p0[e], h0, m0, l0);
                    split3c(p1[e], h1, m1, l1);
                    int n = q8 * 4 + i * 32 + e;
                    ((unsigned*)Bhi)[n * 20 + kp] = (unsigned)h0 | ((unsigned)h1 << 16);
                    ((unsigned*)Bmd)[n * 20 + kp] = (unsigned)m0 | ((unsigned)m1 << 16);
                    ((unsigned*)Blo)[n * 20 + kp] = (unsigned)l0 | ((unsigned)l1 << 16);
                }
            }
        } else {
#pragma unroll
            for (int i = 0; i < 8; ++i) {
                float4 r = regs[i];
                ushort h0, m0, l0, h1, m1, l1, h2, m2, l2, h3, m3, l3;
                split3c(r.x, h0, m0, l0);
                split3c(r.y, h1, m1, l1);
                split3c(r.z, h2, m2, l2);
                split3c(r.w, h3, m3, l3);
                uint2 h = {(unsigned)h0 | ((unsigned)h1 << 16),
                           (unsigned)h2 | ((unsigned)h3 << 16)};
                uint2 m = {(unsigned)m0 | ((unsigned)m1 << 16),
                           (unsigned)m2 | ((unsigned)m3 << 16)};
                uint2 l = {(unsigned)l0 | ((unsigned)l1 << 16),
                           (unsigned)l2 | ((unsigned)l3 << 16)};
                *(uint2*)&Ahi[arow * 40 + i * 4] = h;
                *(uint2*)&Amd[arow * 40 + i * 4] = m;
                *(uint2*)&Alo[arow * 40 + i * 4] = l;
            }
        }
    };

    LOADR(0);
    for (int ks = 0; ks < 8; ++ks) {
        WRITE();
        __syncthreads();
        if (ks < 7) LOADR(ks + 1);

        bf16x8 ah[4], ad[4];
#pragma unroll
        for (int mt = 0; mt < 4; ++mt) {
            int row = wm * 64 + mt * 16 + lr;
            ah[mt] = ld8(&Ahi[row * 40 + q * 8]);
            ad[mt] = ld8(&Amd[row * 40 + q * 8]);
        }
#pragma unroll
        for (int nt = 0; nt < 4; ++nt) {
            int row = wn * 64 + nt * 16 + lr;
            bf16x8 bh = ld8(&Bhi[row * 40 + q * 8]);
            bf16x8 bd = ld8(&Bmd[row * 40 + q * 8]);
            bf16x8 bl = ld8(&Blo[row * 40 + q * 8]);
#pragma unroll
            for (int mt = 0; mt < 4; ++mt) {
                accS[mt][nt] = __builtin_amdgcn_mfma_f32_16x16x32_bf16(ah[mt], bd, accS[mt][nt], 0, 0, 0);
                accS[mt][nt] = __builtin_amdgcn_mfma_f32_16x16x32_bf16(ad[mt], bh, accS[mt][nt], 0, 0, 0);
                accS[mt][nt] = __builtin_amdgcn_mfma_f32_16x16x32_bf16(ad[mt], bd, accS[mt][nt], 0, 0, 0);
                accS[mt][nt] = __builtin_amdgcn_mfma_f32_16x16x32_bf16(ah[mt], bl, accS[mt][nt], 0, 0, 0);
                accM[mt][nt] = __builtin_amdgcn_mfma_f32_16x16x32_bf16(ah[mt], bh, accM[mt][nt], 0, 0, 0);
            }
        }
        bf16x8 al[4];
#pragma unroll
        for (int mt = 0; mt < 4; ++mt) {
            int row = wm * 64 + mt * 16 + lr;
            al[mt] = ld8(&Alo[row * 40 + q * 8]);
        }
#pragma unroll
        for (int nt = 0; nt < 4; ++nt) {
            int row = wn * 64 + nt * 16 + lr;
            bf16x8 bh2 = ld8(&Bhi[row * 40 + q * 8]);
#pragma unroll
            for (int mt = 0; mt < 4; ++mt)
                accS[mt][nt] = __builtin_amdgcn_mfma_f32_16x16x32_bf16(al[mt], bh2, accS[mt][nt], 0, 0, 0);
        }
        __syncthreads();
    }

    const size_t bbase = (size_t)b << 20;
    const int tb = Nblk * 128 + wn * 64 + lr;
    int offN[4];
#pragma unroll
    for (int nt = 0; nt < 4; ++nt) {
        int t = tb + nt * 16;
        offN[nt] = ((t >> 11) & 1) * 65536 + ((t >> 5) & 1) * 32768
                 + ((t >> 6) & 31) * 32 + (t & 31);
    }
#pragma unroll
    for (int mt = 0; mt < 4; ++mt) {
#pragma unroll
        for (int r = 0; r < 4; ++r) {
            int oc = Mblk * 128 + wm * 64 + mt * 16 + q * 4 + r;
            float bias = bias_g[oc];
            size_t offM = (size_t)(oc >> 5) * 131072 + (size_t)(oc & 31) * 1024;
#pragma unroll
            for (int nt = 0; nt < 4; ++nt)
                dst[bbase + offM + offN[nt]] = accM[mt][nt][r] + accS[mt][nt][r] + bias;
        }
    }
}

// ---------------- K2b: split-bf16 MFMA GEMM (value path) -------------------
__global__ __launch_bounds__(256, 2) void gemm_val_kernel(
    const float* __restrict__ X, const float* __restrict__ gmu,
    const float* __restrict__ W,
    const float* __restrict__ bias_g,
    float* __restrict__ dst)
{
    __shared__ __align__(16) ushort Ahi[128 * 40];
    __shared__ __align__(16) ushort Amd[128 * 40];
    __shared__ __align__(16) ushort Bhi[128 * 40];
    __shared__ __align__(16) ushort Bmd[128 * 40];

    const int tid  = threadIdx.x;
    const int Nblk = blockIdx.x, Mblk = blockIdx.y, b = blockIdx.z;
    const int lane = tid & 63, wav = tid >> 6;
    const int wm = wav >> 1, wn = wav & 1;
    const int lr = lane & 15, q = lane >> 4;

    f32x4 acc[4][4];
#pragma unroll
    for (int i = 0; i < 4; ++i)
#pragma unroll
        for (int j = 0; j < 4; ++j) acc[i][j] = (f32x4){0.f, 0.f, 0.f, 0.f};

    const bool isB = (tid < 128);
    float4 regs[8];
    float gval0 = 0.f, gval1 = 0.f;
    const float* srcB = X;
    const float* wrow = W;
    int kp = 0, q8 = 0, arow = 0;
    if (isB) {
        kp = tid >> 3; q8 = tid & 7;
        srcB = X + ((size_t)b << 20) + (size_t)(2 * kp) * 4096 + Nblk * 128 + q8 * 4;
    } else {
        arow = tid - 128;
        int o = Mblk * 128 + arow;
        wrow = W + (size_t)o * 256;
    }

    auto LOADR = [&](int ks) {
        const int k0 = ks * 32;
        if (isB) {
            const float* p = srcB + (size_t)k0 * 4096;
#pragma unroll
            for (int i = 0; i < 4; ++i) {
                regs[i]     = *(const float4*)(p + i * 32);
                regs[i + 4] = *(const float4*)(p + 4096 + i * 32);
            }
            gval0 = gmu[b * 256 + k0 + 2 * kp];
            gval1 = gmu[b * 256 + k0 + 2 * kp + 1];
        } else {
            const float* p = wrow + k0;
#pragma unroll
            for (int i = 0; i < 8; ++i) regs[i] = *(const float4*)(p + i * 4);
        }
    };

    auto WRITE = [&]() {
        if (isB) {
#pragma unroll
            for (int i = 0; i < 4; ++i) {
                float4 r0 = regs[i], r1 = regs[i + 4];
                r0.x += gval0; r0.y += gval0; r0.z += gval0; r0.w += gval0;
                r1.x += gval1; r1.y += gval1; r1.z += gval1; r1.w += gval1;
                const float* p0 = &r0.x;
                const float* p1 = &r1.x;
#pragma unroll
                for (int e = 0; e < 4; ++e) {
                    unsigned h0, m0, l0, h1, m1, l1;
                    split3rn(p0[e], h0, m0, l0);
                    split3rn(p1[e], h1, m1, l1);
                    int n = q8 * 4 + i * 32 + e;
                    ((unsigned*)Bhi)[n * 20 + kp] = h0 | (h1 << 16);
                    ((unsigned*)Bmd)[n * 20 + kp] = m0 | (m1 << 16);
                }
            }
        } else {
#pragma unroll
            for (int i = 0; i < 8; ++i) {
                float4 r = regs[i];
                unsigned h0, m0, l0, h1, m1, l1, h2, m2, l2, h3, m3, l3;
                split3rn(r.x, h0, m0, l0);
                split3rn(r.y, h1, m1, l1);
                split3rn(r.z, h2, m2, l2);
                split3rn(r.w, h3, m3, l3);
                uint2 h = {h0 | (h1 << 16), h2 | (h3 << 16)};
                uint2 m = {m0 | (m1 << 16), m2 | (m3 << 16)};
                *(uint2*)&Ahi[arow * 40 + i * 4] = h;
                *(uint2*)&Amd[arow * 40 + i * 4] = m;
            }
        }
    };

    LOADR(0);
    for (int ks = 0; ks < 8; ++ks) {
        WRITE();
        __syncthreads();
        if (ks < 7) LOADR(ks + 1);
        bf16x8 ah[4], ad[4];
#pragma unroll
        for (int mt = 0; mt < 4; ++mt) {
            int row = wm * 64 + mt * 16 + lr;
            ah[mt] = ld8(&Ahi[row * 40 + q * 8]);
            ad[mt] = ld8(&Amd[row * 40 + q * 8]);
        }
#pragma unroll
        for (int nt = 0; nt < 4; ++nt) {
            int row = wn * 64 + nt * 16 + lr;
            bf16x8 bh = ld8(&Bhi[row * 40 + q * 8]);
            bf16x8 bd = ld8(&Bmd[row * 40 + q * 8]);
#pragma unroll
            for (int mt = 0; mt < 4; ++mt) {
                acc[mt][nt] = __builtin_amdgcn_mfma_f32_16x16x32_bf16(ah[mt], bd, acc[mt][nt], 0, 0, 0);
                acc[mt][nt] = __builtin_amdgcn_mfma_f32_16x16x32_bf16(ad[mt], bh, acc[mt][nt], 0, 0, 0);
                acc[mt][nt] = __builtin_amdgcn_mfma_f32_16x16x32_bf16(ah[mt], bh, acc[mt][nt], 0, 0, 0);
            }
        }
        __syncthreads();
    }

    const size_t bbase = (size_t)b << 20;
    const int tb = Nblk * 128 + wn * 64 + lr;
    int offN[4];
#pragma unroll
    for (int nt = 0; nt < 4; ++nt) {
        int t = tb + nt * 16;
        offN[nt] = ((t >> 11) & 1) * 65536 + ((t >> 5) & 1) * 32768
                 + ((t >> 6) & 31) * 32 + (t & 31);
    }
#pragma unroll
    for (int mt = 0; mt < 4; ++mt) {
#pragma unroll
        for (int r = 0; r < 4; ++r) {
            int oc = Mblk * 128 + wm * 64 + mt * 16 + q * 4 + r;
            float bias = bias_g[oc];
            size_t offM = (size_t)(oc >> 5) * 131072 + (size_t)(oc & 31) * 1024;
#pragma unroll
            for (int nt = 0; nt < 4; ++nt)
                dst[bbase + offM + offN[nt]] = acc[mt][nt][r] + bias;
        }
    }
}

// ---------------- K3a0: streaming 4x4 pooling (both tensors) ---------------
// Replaces the memory-latency-bound front half of the old centers_kernel.
// 2048 blocks, 16 independent float4 loads/thread, no LDS, no barriers ->
// enough loads in flight to run at HBM BW. Accumulation order is
// bit-identical to the old pooling loop: r=(x+y)+(z+w), rows i=0..3 ascending.
// Output layout pzg[src][bp][g][c] (g-major) so the MLP kernel reads it
// conflict-free.
__global__ __launch_bounds__(256) void pool_kernel(
    const float* __restrict__ xqb, const float* __restrict__ valb,
    float* __restrict__ pzg)
{
    const int bp   = blockIdx.x;
    const int srci = blockIdx.y;
    const int ch   = blockIdx.z;   // channel half: c = ch*16 + cl
    const float* src = (srci ? valb : xqb) + (size_t)bp * 32768 + ch * 16384;
    const int t  = threadIdx.x;
    const int cl = t >> 4;         // 0..15
    const int gh = (t >> 1) & 7;   // 0..7
    const int s  = t & 1;          // 0..1 ; gw = s*4 + j

    const float* p0 = src + cl * 1024 + gh * 4;
    float acc[4];
#pragma unroll
    for (int j = 0; j < 4; ++j) {
        const float* p = p0 + (s * 4 + j) * 128;
        float a = 0.f;
#pragma unroll
        for (int i = 0; i < 4; ++i) {
            float4 v = *(const float4*)(p + i * 32);
            a += (v.x + v.y) + (v.z + v.w);
        }
        acc[j] = a * 0.0625f;
    }
    float* dstb = pzg + (size_t)(srci * 512 + bp) * 2048 + (ch * 16 + cl);
#pragma unroll
    for (int j = 0; j < 4; ++j) {
        int g = (s * 4 + j) * 8 + gh;
        dstb[g * 32] = acc[j];
    }
}

// ---------------- K3a1: centers MLP + avg2 + maxpool (conflict-free) -------
// Reads only the 8 KB pooled tile per block. LDS layouts chosen for zero
// bank conflicts: pz as [g*32+c] (stride-1 / broadcast), w1 transposed to
// [c*53+h] (stride-1 across lanes), w2 kept [c*53+h] (odd stride 53).
// MLP2 output aliases the dead pz buffer. All FMA/accumulation orders match
// the old centers_kernel bit-for-bit.
__global__ __launch_bounds__(256) void centers_mlp_kernel(
    const float* __restrict__ pzg,
    const float* __restrict__ w1g, const float* __restrict__ b1g,
    const float* __restrict__ w2g, const float* __restrict__ b2g,
    float* __restrict__ cenbuf)
{
    const int bp   = blockIdx.x;
    const int srci = blockIdx.y;
    const int t    = threadIdx.x;

    __shared__ float pzs[2048];        // [g][c]; reused as MLP2 output
    __shared__ float ybuf[64 * HID];
    __shared__ float w1t[32 * HID];    // transposed: [c][h]
    __shared__ float w2s[32 * HID];    // [c][h]
    __shared__ float b1s[56];
    __shared__ float b2s[32];
    __shared__ float avg2[128];

    const float* psrc = pzg + (size_t)(srci * 512 + bp) * 2048;
    for (int i = t; i < 2048; i += 256) pzs[i] = psrc[i];
    for (int i = t; i < 32 * HID; i += 256) {
        int h = i >> 5, c = i & 31;
        w1t[c * HID + h] = w1g[i];
        w2s[i] = w2g[i];
    }
    if (t < HID) b1s[t] = b1g[t];
    if (t < 32) b2s[t] = b2g[t];
    __syncthreads();

    if (t < 128) {
        int qq = t >> 5, c = t & 31, qw = qq >> 1, qh = qq & 1;
        float s = 0.f;
        for (int a = 0; a < 4; ++a)
            for (int e = 0; e < 4; ++e)
                s += pzs[((qw * 4 + a) * 8 + (qh * 4 + e)) * 32 + c];
        avg2[t] = s * 0.0625f;
    }
    for (int tt = t; tt < 64 * HID; tt += 256) {
        int g = tt / HID, h = tt - g * HID;
        float a = b1s[h];
        for (int c = 0; c < 32; ++c)
            a = fmaf(pzs[g * 32 + c], w1t[c * HID + h], a);
        ybuf[g * HID + h] = 0.5f * a * (1.f + erff(a * 0.70710678118654752f));
    }
    __syncthreads();

    for (int tt = t; tt < 2048; tt += 256) {
        int g = tt >> 5, c = tt & 31;
        float a = b2s[c];
        for (int h = 0; h < HID; ++h)
            a = fmaf(ybuf[g * HID + h], w2s[c * HID + h], a);
        pzs[tt] = a;   // out2[g*32+c]
    }
    __syncthreads();

    if (t < 128) {
        int qq = t >> 5, c = t & 31, qw = qq >> 1, qh = qq & 1;
        float m = -1e30f;
        for (int a = 0; a < 4; ++a)
            for (int e = 0; e < 4; ++e)
                m = fmaxf(m, pzs[((qw * 4 + a) * 8 + qh * 4 + e) * 32 + c]);
        cenbuf[srci * 65536 + bp * 128 + t] = avg2[t] + m;
    }
}

// ---------------- K3b: assign + combine (no dispatch write) ----------------
__global__ __launch_bounds__(1024) void assign_kernel(
    const float* __restrict__ xqb, const float* __restrict__ valb,
    const float* __restrict__ cenbuf,
    const float* __restrict__ alphap, const float* __restrict__ betap,
    float* __restrict__ wbpk, float* __restrict__ outcg)
{
    const int bp = blockIdx.x;
    const int n  = threadIdx.x;
    const int lane = n & 63;

    __shared__ float cen0s[128], cen1s[128];
    __shared__ float wbuf[1024];
    __shared__ int   bbuf[1024];
    __shared__ float csum[32][4];
    __shared__ float ccnt[4];

    if (n < 128) cen0s[n] = cenbuf[bp * 128 + n];
    else if (n < 256) cen1s[n - 128] = cenbuf[65536 + bp * 128 + (n - 128)];
    if (n < 4) ccnt[n] = 0.f;
    __syncthreads();

    float rn[4];
#pragma unroll
    for (int m = 0; m < 4; ++m) {
        float ssn = 0.f;
        for (int c = 0; c < 32; ++c) { float tt = cen0s[m * 32 + c]; ssn += tt * tt; }
        rn[m] = 1.f / fmaxf(sqrtf(ssn), 1e-12f);
    }

    const float* px = xqb + (size_t)bp * 32768 + n;
    float ss = 0.f, d0 = 0.f, d1 = 0.f, d2 = 0.f, d3 = 0.f;
#pragma unroll
    for (int c = 0; c < 32; ++c) {
        float v = px[(size_t)c << 10];
        ss += v * v;
        d0 += cen0s[0 * 32 + c] * v;
        d1 += cen0s[1 * 32 + c] * v;
        d2 += cen0s[2 * 32 + c] * v;
        d3 += cen0s[3 * 32 + c] * v;
    }
    const float rx = 1.f / fmaxf(sqrtf(ss), 1e-12f);
    const float alpha = alphap[0], beta = betap[0];
    float dm[4] = {d0, d1, d2, d3};
    float best = -1.f;
    int bidx = 0;
#pragma unroll
    for (int m = 0; m < 4; ++m) {
        float t = beta + alpha * (dm[m] * rn[m] * rx);
        float s = 1.f / (1.f + expf(-t));
        if (m == 0 || s > best) { best = s; bidx = m; }
    }
    wbuf[n] = best;
    bbuf[n] = bidx;
    wbpk[(size_t)bp * 1024 + n] = u2f((f2u(best) & ~3u) | (unsigned)bidx);

#pragma unroll
    for (int m = 0; m < 4; ++m) {
        unsigned long long bl = __ballot(bidx == m);
        if (lane == 0) atomicAdd(&ccnt[m], (float)__popcll(bl));
    }
    __syncthreads();

    {
        const int c = n >> 5, l = n & 31;
        const float* pv = valb + (size_t)bp * 32768 + c * 1024 + l;
        float a0 = 0.f, a1 = 0.f, a2 = 0.f, a3 = 0.f;
#pragma unroll
        for (int i = 0; i < 32; ++i) {
            float v = pv[i * 32];
            int t = i * 32 + l;
            float p = wbuf[t] * v;
            int m = bbuf[t];
            a0 += (m == 0) ? p : 0.f;
            a1 += (m == 1) ? p : 0.f;
            a2 += (m == 2) ? p : 0.f;
            a3 += (m == 3) ? p : 0.f;
        }
#pragma unroll
        for (int off = 1; off < 32; off <<= 1) {
            a0 += __shfl_xor(a0, off);
            a1 += __shfl_xor(a1, off);
            a2 += __shfl_xor(a2, off);
            a3 += __shfl_xor(a3, off);
        }
        if (l == 0) {
            csum[c][0] = a0; csum[c][1] = a1; csum[c][2] = a2; csum[c][3] = a3;
        }
    }
    __syncthreads();
    if (n < 128)
        outcg[(size_t)bp * 128 + n] =
            (csum[n & 31][n >> 5] + cen1s[n]) / (ccnt[n >> 5] + 1.f);
}

// ---------------- K4a: P[bp][m][o] = sum_c w2[o, head*32+c] * outc[m][c] ---
__global__ __launch_bounds__(256) void pmat_kernel(
    const float* __restrict__ outcg, const float* __restrict__ w2,
    float* __restrict__ P)
{
    const int bp = blockIdx.x;
    const int o  = threadIdx.x;
    __shared__ float oc[128];
    if (o < 128) oc[o] = outcg[(size_t)bp * 128 + o];
    __syncthreads();
    const int head = (bp >> 2) & 7;
    const float* wrow = w2 + (size_t)o * 256 + head * 32;
    float a0 = 0.f, a1 = 0.f, a2 = 0.f, a3 = 0.f;
#pragma unroll
    for (int c = 0; c < 32; ++c) {
        float wv = wrow[c];
        a0 = fmaf(wv, oc[c], a0);
        a1 = fmaf(wv, oc[32 + c], a1);
        a2 = fmaf(wv, oc[64 + c], a2);
        a3 = fmaf(wv, oc[96 + c], a3);
    }
    float* pb = P + (size_t)bp * 1024;
    pb[0 * 256 + o] = a0;
    pb[1 * 256 + o] = a1;
    pb[2 * 256 + o] = a2;
    pb[3 * 256 + o] = a3;
}

// ---------------- K4b: fused dispatch + fc2 --------------------------------
__global__ __launch_bounds__(1024) void fc2_dispatch_kernel(
    const float* __restrict__ P, const float* __restrict__ wbpk,
    const float* __restrict__ b2, float* __restrict__ out)
{
    const int ogrp = blockIdx.x, quad = blockIdx.y, b = blockIdx.z;
    const int n = threadIdx.x;
    const int wl = n >> 5, hl = n & 31;

    __shared__ float Pl[8][4][68];
    __shared__ float b2s[64];

    for (int i = n; i < 2048; i += 1024) {
        int h = i >> 8, rm = i & 255;
        int m = rm >> 6, j = rm & 63;
        int bp = b * 32 + h * 4 + quad;
        Pl[h][m][j] = P[(size_t)bp * 1024 + m * 256 + ogrp * 64 + j];
    }
    if (n < 64) b2s[n] = b2[ogrp * 64 + n];
    __syncthreads();

    float bst[8];
    int   mm[8];
#pragma unroll
    for (int h = 0; h < 8; ++h) {
        int bp = b * 32 + h * 4 + quad;
        unsigned u = f2u(wbpk[(size_t)bp * 1024 + n]);
        mm[h]  = (int)(u & 3u);
        bst[h] = u2f(u & ~3u);
    }

    const int fi = quad >> 1, fj = quad & 1;
    float* obp = out + (size_t)b * 1048576 + (size_t)ogrp * 64 * 4096
               + (size_t)(fi * 32 + wl) * 64 + (fj * 32 + hl);
#pragma unroll 4
    for (int j = 0; j < 64; ++j) {
        float s = b2s[j];
#pragma unroll
        for (int h = 0; h < 8; ++h)
            s = fmaf(bst[h], Pl[h][mm[h]][j], s);
        obp[(size_t)j * 4096] = s;
    }
}

// ---------------- launch ----------------
extern "C" void kernel_launch(void* const* d_in, const int* in_sizes, int n_in,
                              void* d_out, int out_size, void* d_ws, size_t ws_size,
                              hipStream_t stream) {
    const float* x     = (const float*)d_in[0];
    const float* gap   = (const float*)d_in[1];
    const float* wq    = (const float*)d_in[2];
    const float* bq    = (const float*)d_in[3];
    const float* wv    = (const float*)d_in[4];
    const float* bv    = (const float*)d_in[5];
    const float* w2    = (const float*)d_in[6];
    const float* b2    = (const float*)d_in[7];
    const float* alpha = (const float*)d_in[8];
    const float* beta  = (const float*)d_in[9];
    const float* ow1   = (const float*)d_in[10];
    const float* ob1   = (const float*)d_in[11];
    const float* ow2   = (const float*)d_in[12];
    const float* ob2   = (const float*)d_in[13];

    float* out  = (float*)d_out;
    float* gmu  = (float*)d_ws;                   // 4096
    float* valb = gmu + 4096;                     // 16.7M
    float* cenb = valb + (size_t)16777216;        // 131072
    float* wbpk = cenb + 131072;                  // 524288
    float* outc = wbpk + 524288;                  // 65536
    float* pmat = outc + 65536;                   // 524288
    float* pzg  = pmat + 524288;                  // 2097152 (8.4 MB pooled)
    float* xqb  = out;                            // d_out reused as xq scratch

    mean_kernel<<<4096, 256, 0, stream>>>(x, gap, gmu);
    gemm_xq6_kernel<<<dim3(32, 2, 16), 256, 0, stream>>>(x, gmu, wq, bq, xqb);
    gemm_val_kernel<<<dim3(32, 2, 16), 256, 0, stream>>>(x, gmu, wv, bv, valb);
    pool_kernel<<<dim3(512, 2, 2), 256, 0, stream>>>(xqb, valb, pzg);
    centers_mlp_kernel<<<dim3(512, 2), 256, 0, stream>>>(
        pzg, ow1, ob1, ow2, ob2, cenb);
    assign_kernel<<<512, 1024, 0, stream>>>(
        xqb, valb, cenb, alpha, beta, wbpk, outc);
    pmat_kernel<<<512, 256, 0, stream>>>(outc, w2, pmat);
    fc2_dispatch_kernel<<<dim3(4, 4, 16), 1024, 0, stream>>>(
        pmat, wbpk, b2, out);
}